// Round 2
// baseline (63.541 us; speedup 1.0000x reference)
//
#include <hip/hip_runtime.h>
#include <math.h>

#define BATCH   512
#define NPATCH  196   // 14*14

// ---------------------------------------------------------------------------
// Kernel A: batch-major -> patch-major transpose.
// Block b reads x[b][784] coalesced (196 x float4), stages in LDS, writes
// ws[p*512 + b] = {x[2r][2c], x[2r][2c+1], x[2r+1][2c], x[2r+1][2c+1]}.
// Writes are scattered (stride 8 KB) but fire-and-forget; ~6 MB total.
// ---------------------------------------------------------------------------
__global__ __launch_bounds__(256) void patch_kernel(const float* __restrict__ x,
                                                    float4* __restrict__ ws) {
    __shared__ float lx[784];
    const int b = blockIdx.x;
    const int t = threadIdx.x;
    if (t < 196) {
        ((float4*)lx)[t] = ((const float4*)(x + b * 784))[t];
    }
    __syncthreads();
    if (t < 196) {
        const int r = t / 14, c = t - r * 14;
        const float* row = lx + (2 * r) * 28 + 2 * c;
        float4 v;
        v.x = row[0];
        v.y = row[1];
        v.z = row[28];
        v.w = row[29];
        ws[t * BATCH + b] = v;
    }
}

// ---------------------------------------------------------------------------
// Gate primitives: state idx = w0*8 + w1*4 + w2*2 + w3 (wire 0 = MSB).
// MASK = 8 >> wire. Fully unrolled -> arrays in VGPRs.
// ---------------------------------------------------------------------------
template <int MASK>
__device__ __forceinline__ void ry_real(float* s, float c, float sn) {
    #pragma unroll
    for (int i = 0; i < 16; ++i) {
        if (!(i & MASK)) {
            const int j = i | MASK;
            float a0 = s[i], a1 = s[j];
            s[i] = c * a0 - sn * a1;
            s[j] = sn * a0 + c * a1;
        }
    }
}

template <int MASK>
__device__ __forceinline__ void ry_cplx(float* sr, float* si, float c, float sn) {
    #pragma unroll
    for (int i = 0; i < 16; ++i) {
        if (!(i & MASK)) {
            const int j = i | MASK;
            float a0 = sr[i], a1 = sr[j];
            sr[i] = c * a0 - sn * a1;
            sr[j] = sn * a0 + c * a1;
            float b0 = si[i], b1 = si[j];
            si[i] = c * b0 - sn * b1;
            si[j] = sn * b0 + c * b1;
        }
    }
}

template <int CMASK, int TMASK>
__device__ __forceinline__ void cnot_real(float* s) {
    #pragma unroll
    for (int i = 0; i < 16; ++i) {
        if ((i & CMASK) && !(i & TMASK)) {
            const int j = i | TMASK;
            float t = s[i]; s[i] = s[j]; s[j] = t;
        }
    }
}

template <int CMASK, int TMASK>
__device__ __forceinline__ void cnot_cplx(float* sr, float* si) {
    #pragma unroll
    for (int i = 0; i < 16; ++i) {
        if ((i & CMASK) && !(i & TMASK)) {
            const int j = i | TMASK;
            float t;
            t = sr[i]; sr[i] = sr[j]; sr[j] = t;
            t = si[i]; si[i] = si[j]; si[j] = t;
        }
    }
}

// ---------------------------------------------------------------------------
// Kernel B: one block per patch location (196 x 512). Thread t owns batch t:
// ONE coalesced float4 load from ws, stats reduce, circuit, write.
// Layer-0 RZs collapsed into one diagonal phase table; layer-1 RZs dropped
// (diagonal before |.|^2 measurement).
// ---------------------------------------------------------------------------
__global__ __launch_bounds__(512) void circuit_kernel(const float4* __restrict__ ws,
                                                      const float* __restrict__ params,
                                                      float* __restrict__ out) {
    __shared__ float s_ryc[16], s_rys[16];
    __shared__ float s_pc[16], s_ps[16];
    __shared__ float s_sum[8], s_sq[8];

    const int p = blockIdx.x;             // 0..195
    const int t = threadIdx.x;            // 0..511

    // ---- coalesced patch load first (hide latency under table setup) ----
    const float4 v = ws[p * BATCH + t];

    // ---- thread-uniform gate tables, once per block ----
    if (t < 16) {
        const int l = t >> 3, set = (t >> 2) & 1, w = t & 3;
        float sn, cs;
        __sincosf(0.5f * params[l * 12 + w * 3 + set], &sn, &cs);
        s_ryc[t] = cs;
        s_rys[t] = sn;
    } else if (t < 32) {
        const int i = t - 16;
        const float h0 = 0.5f * params[2];
        const float h1 = 0.5f * params[5];
        const float h2 = 0.5f * params[8];
        const float h3 = 0.5f * params[11];
        const float alpha = ((i & 8) ? h0 : -h0) + ((i & 4) ? h1 : -h1)
                          + ((i & 2) ? h2 : -h2) + ((i & 1) ? h3 : -h3);
        float sn, cs;
        __sincosf(alpha, &sn, &cs);
        s_pc[i] = cs;
        s_ps[i] = sn;
    }

    // ---- per-location normalization stats over 512*4 values ----
    float sum = v.x + v.y + v.z + v.w;
    float sq  = v.x * v.x + v.y * v.y + v.z * v.z + v.w * v.w;
    #pragma unroll
    for (int off = 32; off; off >>= 1) {
        sum += __shfl_down(sum, off, 64);
        sq  += __shfl_down(sq,  off, 64);
    }
    const int wave = t >> 6, lane = t & 63;
    if (lane == 0) { s_sum[wave] = sum; s_sq[wave] = sq; }
    __syncthreads();

    // all threads redundantly combine (no second barrier, no serial tail)
    float S = 0.f, Q = 0.f;
    #pragma unroll
    for (int w = 0; w < 8; ++w) { S += s_sum[w]; Q += s_sq[w]; }
    const float n   = (float)(BATCH * 4);
    const float m   = S / n;
    const float var = (Q - S * S / n) / (n - 1.0f);
    const float sd  = sqrtf(fmaxf(var, 0.f));
    // angle = (val - m)/(sd + 1e-8) * pi; gates use theta/2 -> fold the 0.5
    const float invh = 0.5f * 3.14159265358979323846f / (sd + 1e-8f);

    // ---- input RY half-angles ----
    float c0, s0, c1, s1, c2, s2, c3, s3;
    __sincosf((v.x - m) * invh, &s0, &c0);
    __sincosf((v.y - m) * invh, &s1, &c1);
    __sincosf((v.z - m) * invh, &s2, &c2);
    __sincosf((v.w - m) * invh, &s3, &c3);

    // ---- initial product state (REAL) ----
    float sr[16];
    {
        const float cc01 = c0 * c1, cs01 = c0 * s1, sc01 = s0 * c1, ss01 = s0 * s1;
        const float cc23 = c2 * c3, cs23 = c2 * s3, sc23 = s2 * c3, ss23 = s2 * s3;
        #pragma unroll
        for (int i = 0; i < 16; ++i) {
            const float hi = (i & 8) ? ((i & 4) ? ss01 : sc01) : ((i & 4) ? cs01 : cc01);
            const float lo = (i & 2) ? ((i & 1) ? ss23 : sc23) : ((i & 1) ? cs23 : cc23);
            sr[i] = hi * lo;
        }
    }

    // ---- layer 0: all-real RYs + CNOTs ----
    ry_real<8>(sr, s_ryc[0], s_rys[0]);
    ry_real<4>(sr, s_ryc[1], s_rys[1]);
    ry_real<2>(sr, s_ryc[2], s_rys[2]);
    ry_real<1>(sr, s_ryc[3], s_rys[3]);
    cnot_real<8, 4>(sr);
    cnot_real<4, 2>(sr);
    cnot_real<2, 1>(sr);
    ry_real<8>(sr, s_ryc[4], s_rys[4]);
    ry_real<4>(sr, s_ryc[5], s_rys[5]);
    ry_real<2>(sr, s_ryc[6], s_rys[6]);
    ry_real<1>(sr, s_ryc[7], s_rys[7]);
    cnot_real<4, 8>(sr);
    cnot_real<2, 4>(sr);
    cnot_real<1, 2>(sr);

    // ---- layer-0 RZs: combined diagonal phase on the real state ----
    float si[16];
    #pragma unroll
    for (int i = 0; i < 16; ++i) {
        si[i] = sr[i] * s_ps[i];
        sr[i] = sr[i] * s_pc[i];
    }

    // ---- layer 1: complex RYs + CNOTs; trailing RZs dropped ----
    ry_cplx<8>(sr, si, s_ryc[8],  s_rys[8]);
    ry_cplx<4>(sr, si, s_ryc[9],  s_rys[9]);
    ry_cplx<2>(sr, si, s_ryc[10], s_rys[10]);
    ry_cplx<1>(sr, si, s_ryc[11], s_rys[11]);
    cnot_cplx<8, 4>(sr, si);
    cnot_cplx<4, 2>(sr, si);
    cnot_cplx<2, 1>(sr, si);
    ry_cplx<8>(sr, si, s_ryc[12], s_rys[12]);
    ry_cplx<4>(sr, si, s_ryc[13], s_rys[13]);
    ry_cplx<2>(sr, si, s_ryc[14], s_rys[14]);
    ry_cplx<1>(sr, si, s_ryc[15], s_rys[15]);
    cnot_cplx<4, 8>(sr, si);
    cnot_cplx<2, 4>(sr, si);
    cnot_cplx<1, 2>(sr, si);

    // ---- probabilities + Walsh-tree Z expectations ----
    float pr[16];
    #pragma unroll
    for (int i = 0; i < 16; ++i) pr[i] = sr[i] * sr[i] + si[i] * si[i];

    float a[8], z3 = 0.f;
    #pragma unroll
    for (int k = 0; k < 8; ++k) {
        a[k] = pr[2 * k] + pr[2 * k + 1];
        z3  += pr[2 * k] - pr[2 * k + 1];
    }
    float b4[4], z2 = 0.f;
    #pragma unroll
    for (int k = 0; k < 4; ++k) {
        b4[k] = a[2 * k] + a[2 * k + 1];
        z2   += a[2 * k] - a[2 * k + 1];
    }
    float g2[2], z1 = 0.f;
    #pragma unroll
    for (int k = 0; k < 2; ++k) {
        g2[k] = b4[2 * k] + b4[2 * k + 1];
        z1   += b4[2 * k] - b4[2 * k + 1];
    }
    const float z0 = g2[0] - g2[1];

    *(float4*)(out + t * (NPATCH * 4) + p * 4) = make_float4(z0, z1, z2, z3);
}

extern "C" void kernel_launch(void* const* d_in, const int* in_sizes, int n_in,
                              void* d_out, int out_size, void* d_ws, size_t ws_size,
                              hipStream_t stream) {
    (void)in_sizes; (void)n_in; (void)ws_size; (void)out_size;
    const float* x      = (const float*)d_in[0];   // (512, 28, 28) fp32
    const float* params = (const float*)d_in[1];   // (2, 4, 3) fp32
    float*       out    = (float*)d_out;           // (512, 784) fp32
    float4*      ws     = (float4*)d_ws;           // >= 196*512*16 B = 1.6 MB

    patch_kernel<<<BATCH, 256, 0, stream>>>(x, ws);
    circuit_kernel<<<NPATCH, 512, 0, stream>>>(ws, params, out);
}

// Round 3
// 60.713 us; speedup vs baseline: 1.0466x; 1.0466x over previous
//
#include <hip/hip_runtime.h>
#include <math.h>

#define BATCH   512
#define NPATCH  196   // 14*14

// ---------------------------------------------------------------------------
// State idx = w0*8 + w1*4 + w2*2 + w3 (wire 0 = MSB). MASK = 8 >> wire.
// All loops fully unrolled with compile-time indices -> arrays live in VGPRs.
// CNOTs on registers are pure renames (zero instructions after unroll).
// ---------------------------------------------------------------------------
template <int MASK>
__device__ __forceinline__ void ry_real(float* s, float c, float sn) {
    #pragma unroll
    for (int i = 0; i < 16; ++i) {
        if (!(i & MASK)) {
            const int j = i | MASK;
            float a0 = s[i], a1 = s[j];
            s[i] = c * a0 - sn * a1;
            s[j] = sn * a0 + c * a1;
        }
    }
}

template <int MASK>
__device__ __forceinline__ void ry_cplx(float* sr, float* si, float c, float sn) {
    #pragma unroll
    for (int i = 0; i < 16; ++i) {
        if (!(i & MASK)) {
            const int j = i | MASK;
            float a0 = sr[i], a1 = sr[j];
            sr[i] = c * a0 - sn * a1;
            sr[j] = sn * a0 + c * a1;
            float b0 = si[i], b1 = si[j];
            si[i] = c * b0 - sn * b1;
            si[j] = sn * b0 + c * b1;
        }
    }
}

template <int CMASK, int TMASK>
__device__ __forceinline__ void cnot_real(float* s) {
    #pragma unroll
    for (int i = 0; i < 16; ++i) {
        if ((i & CMASK) && !(i & TMASK)) {
            const int j = i | TMASK;
            float t = s[i]; s[i] = s[j]; s[j] = t;
        }
    }
}

template <int CMASK, int TMASK>
__device__ __forceinline__ void cnot_cplx(float* sr, float* si) {
    #pragma unroll
    for (int i = 0; i < 16; ++i) {
        if ((i & CMASK) && !(i & TMASK)) {
            const int j = i | TMASK;
            float t;
            t = sr[i]; sr[i] = sr[j]; sr[j] = t;
            t = si[i]; si[i] = si[j]; si[j] = t;
        }
    }
}

// ---------------------------------------------------------------------------
// Single fused kernel: one block per patch location (196 x 512).
// Thread t owns batch t: stats contribution + ONE circuit.
//
// Algebraic structure:
//  - input RY(angle_w) folded into layer-0 set-0 RY (same axis, adjacent):
//    half-angle h_w = (v_w - m)*invh + 0.5*params[0][w][0]
//  - state purely real through layer 0 (RY/CNOT preserve real)
//  - layer-0 RZs collapsed to one 16-entry diagonal phase table (uniform)
//  - layer-1 RZs dropped entirely (diagonal before |.|^2 measurement)
// ---------------------------------------------------------------------------
__global__ __launch_bounds__(512) void fused_kernel(const float* __restrict__ x,
                                                    const float* __restrict__ params,
                                                    float* __restrict__ out) {
    __shared__ float s_ryc[16], s_rys[16];   // entries 0-3 unused (folded)
    __shared__ float s_pc[16], s_ps[16];
    __shared__ float s_half[4];
    __shared__ float s_sum[8], s_sq[8];

    const int p = blockIdx.x;             // 0..195
    const int r = p / 14, c = p - r * 14;
    const int t = threadIdx.x;            // 0..511

    // ---- issue the gather loads first; latency hides under table setup ----
    const float* base = x + t * 784 + (2 * r) * 28 + 2 * c;
    const float2 a01 = *(const float2*)base;          // v0, v1
    const float2 a23 = *(const float2*)(base + 28);   // v2, v3

    // ---- thread-uniform gate tables, once per block ----
    if (t < 16) {
        const int l = t >> 3, set = (t >> 2) & 1, w = t & 3;
        float sn, cs;
        __sincosf(0.5f * params[l * 12 + w * 3 + set], &sn, &cs);
        s_ryc[t] = cs;
        s_rys[t] = sn;
    } else if (t < 32) {
        const int i = t - 16;
        const float h0 = 0.5f * params[2];
        const float h1 = 0.5f * params[5];
        const float h2 = 0.5f * params[8];
        const float h3 = 0.5f * params[11];
        const float alpha = ((i & 8) ? h0 : -h0) + ((i & 4) ? h1 : -h1)
                          + ((i & 2) ? h2 : -h2) + ((i & 1) ? h3 : -h3);
        float sn, cs;
        __sincosf(alpha, &sn, &cs);
        s_pc[i] = cs;
        s_ps[i] = sn;
    } else if (t < 36) {
        // layer-0 set-0 half-angles, folded into the input rotation
        s_half[t - 32] = 0.5f * params[(t - 32) * 3];
    }

    // ---- per-location normalization stats over 512*4 values ----
    float sum = a01.x + a01.y + a23.x + a23.y;
    float sq  = a01.x * a01.x + a01.y * a01.y + a23.x * a23.x + a23.y * a23.y;
    #pragma unroll
    for (int off = 32; off; off >>= 1) {
        sum += __shfl_down(sum, off, 64);
        sq  += __shfl_down(sq,  off, 64);
    }
    const int wave = t >> 6, lane = t & 63;
    if (lane == 0) { s_sum[wave] = sum; s_sq[wave] = sq; }
    __syncthreads();

    // all threads redundantly combine (no second barrier, no serial tail)
    float S = 0.f, Q = 0.f;
    #pragma unroll
    for (int w = 0; w < 8; ++w) { S += s_sum[w]; Q += s_sq[w]; }
    const float n   = (float)(BATCH * 4);
    const float m   = S / n;
    const float var = (Q - S * S / n) / (n - 1.0f);
    const float sd  = sqrtf(fmaxf(var, 0.f));
    // angle = (val - m)/(sd + 1e-8) * pi; gates use theta/2 -> fold the 0.5
    const float invh = 0.5f * 3.14159265358979323846f / (sd + 1e-8f);

    // ---- input+layer0set0 RY half-angles ----
    float c0, s0, c1, s1, c2, s2, c3, s3;
    __sincosf((a01.x - m) * invh + s_half[0], &s0, &c0);
    __sincosf((a01.y - m) * invh + s_half[1], &s1, &c1);
    __sincosf((a23.x - m) * invh + s_half[2], &s2, &c2);
    __sincosf((a23.y - m) * invh + s_half[3], &s3, &c3);

    // ---- product state after input RY + layer-0 set-0 RY (REAL) ----
    float sr[16];
    {
        const float cc01 = c0 * c1, cs01 = c0 * s1, sc01 = s0 * c1, ss01 = s0 * s1;
        const float cc23 = c2 * c3, cs23 = c2 * s3, sc23 = s2 * c3, ss23 = s2 * s3;
        #pragma unroll
        for (int i = 0; i < 16; ++i) {
            const float hi = (i & 8) ? ((i & 4) ? ss01 : sc01) : ((i & 4) ? cs01 : cc01);
            const float lo = (i & 2) ? ((i & 1) ? ss23 : sc23) : ((i & 1) ? cs23 : cc23);
            sr[i] = hi * lo;
        }
    }

    // ---- layer 0 remainder: CNOTs + RY set1 + reverse CNOTs (all real) ----
    cnot_real<8, 4>(sr);
    cnot_real<4, 2>(sr);
    cnot_real<2, 1>(sr);
    ry_real<8>(sr, s_ryc[4], s_rys[4]);
    ry_real<4>(sr, s_ryc[5], s_rys[5]);
    ry_real<2>(sr, s_ryc[6], s_rys[6]);
    ry_real<1>(sr, s_ryc[7], s_rys[7]);
    cnot_real<4, 8>(sr);
    cnot_real<2, 4>(sr);
    cnot_real<1, 2>(sr);

    // ---- layer-0 RZs: combined diagonal phase on the real state ----
    float si[16];
    #pragma unroll
    for (int i = 0; i < 16; ++i) {
        si[i] = sr[i] * s_ps[i];
        sr[i] = sr[i] * s_pc[i];
    }

    // ---- layer 1: complex RYs + CNOTs; trailing RZs dropped ----
    ry_cplx<8>(sr, si, s_ryc[8],  s_rys[8]);
    ry_cplx<4>(sr, si, s_ryc[9],  s_rys[9]);
    ry_cplx<2>(sr, si, s_ryc[10], s_rys[10]);
    ry_cplx<1>(sr, si, s_ryc[11], s_rys[11]);
    cnot_cplx<8, 4>(sr, si);
    cnot_cplx<4, 2>(sr, si);
    cnot_cplx<2, 1>(sr, si);
    ry_cplx<8>(sr, si, s_ryc[12], s_rys[12]);
    ry_cplx<4>(sr, si, s_ryc[13], s_rys[13]);
    ry_cplx<2>(sr, si, s_ryc[14], s_rys[14]);
    ry_cplx<1>(sr, si, s_ryc[15], s_rys[15]);
    cnot_cplx<4, 8>(sr, si);
    cnot_cplx<2, 4>(sr, si);
    cnot_cplx<1, 2>(sr, si);

    // ---- probabilities + Walsh-tree Z expectations ----
    float pr[16];
    #pragma unroll
    for (int i = 0; i < 16; ++i) pr[i] = sr[i] * sr[i] + si[i] * si[i];

    float a[8], z3 = 0.f;
    #pragma unroll
    for (int k = 0; k < 8; ++k) {
        a[k] = pr[2 * k] + pr[2 * k + 1];
        z3  += pr[2 * k] - pr[2 * k + 1];
    }
    float b4[4], z2 = 0.f;
    #pragma unroll
    for (int k = 0; k < 4; ++k) {
        b4[k] = a[2 * k] + a[2 * k + 1];
        z2   += a[2 * k] - a[2 * k + 1];
    }
    float g2[2], z1 = 0.f;
    #pragma unroll
    for (int k = 0; k < 2; ++k) {
        g2[k] = b4[2 * k] + b4[2 * k + 1];
        z1   += b4[2 * k] - b4[2 * k + 1];
    }
    const float z0 = g2[0] - g2[1];

    *(float4*)(out + t * (NPATCH * 4) + p * 4) = make_float4(z0, z1, z2, z3);
}

extern "C" void kernel_launch(void* const* d_in, const int* in_sizes, int n_in,
                              void* d_out, int out_size, void* d_ws, size_t ws_size,
                              hipStream_t stream) {
    (void)in_sizes; (void)n_in; (void)d_ws; (void)ws_size; (void)out_size;
    const float* x      = (const float*)d_in[0];   // (512, 28, 28) fp32
    const float* params = (const float*)d_in[1];   // (2, 4, 3) fp32
    float*       out    = (float*)d_out;           // (512, 784) fp32

    fused_kernel<<<NPATCH, 512, 0, stream>>>(x, params, out);
}